// Round 2
// baseline (507.237 us; speedup 1.0000x reference)
//
#include <hip/hip_runtime.h>

// StrokeField: mip-NeRF-360 contract + 500-sphere sequential alpha blend.
// VALU-issue-bound (R1: VALUBusy~114%, HBM 1.5%). Strategy: minimize VALU
// instructions per (point,stroke); stroke params via SGPR (s_load) so no
// LDS/VMEM in the inner loop.
//
// Inner loop math (back-to-front, premultiplied transmittance):
//   d2  = |c|^2 + |a|^2 - 2 c.a          (3 fma + 1 add, expanded form)
//   omt = clamp(5*dist + (0.5 - 5r), 0, 1)   == 1 - t
//   Tn = omt*T; tT = T - Tn;  A_{d,r,g,b} += tT * {dp,cr,cg,cb};  T = Tn
// Identical to the forward scan: h = sum_s t_s c_s prod_{j>s} omt_j, hw = prod omt.

__global__ __launch_bounds__(256) void prep_kernel(
    const float* __restrict__ shape, const float* __restrict__ color,
    const float* __restrict__ alpha,
    float4* __restrict__ A, float4* __restrict__ B, float* __restrict__ C,
    int ns)
{
    int s = blockIdx.x * blockDim.x + threadIdx.x;
    if (s >= ns) return;
    float4 sp = ((const float4*)shape)[s];
    float a2 = fmaf(sp.x, sp.x, fmaf(sp.y, sp.y, sp.z * sp.z));
    A[s] = make_float4(sp.x, sp.y, sp.z, a2);
    float K  = fmaf(-5.0f, sp.w, 0.5f);          // 0.5 - 5r
    float dp = fmaxf(alpha[s], 0.0f) * 50.0f;
    B[s] = make_float4(K, dp, color[3 * s], color[3 * s + 1]);
    C[s] = color[3 * s + 2];
}

__device__ __forceinline__ void contract_point(
    const float* __restrict__ coords, int i,
    float& cx, float& cy, float& cz)
{
    float x = coords[3 * i + 0];
    float y = coords[3 * i + 1];
    float z = coords[3 * i + 2];
    float n2 = fmaf(x, x, fmaf(y, y, z * z));
    float nn = fmaxf(__builtin_amdgcn_sqrtf(n2), 1e-9f);
    float invn = 1.0f / nn;
    float sc = (nn <= 1.0f) ? 0.5f : (2.0f - invn) * (0.5f * invn);
    cx = x * sc; cy = y * sc; cz = z * sc;
}

__device__ __forceinline__ void write_out(
    float* __restrict__ out, int i, int n,
    float Ad, float Ar, float Ag, float Ab, float T,
    float cx, float cy, float cz)
{
    float inv = 1.0f / (1.0f + 1e-6f - T);
    out[i] = Ad;
    float* rgb = out + n;
    rgb[3 * i + 0] = fminf(fmaxf(Ar * inv, 0.0f), 1.0f);
    rgb[3 * i + 1] = fminf(fmaxf(Ag * inv, 0.0f), 1.0f);
    rgb[3 * i + 2] = fminf(fmaxf(Ab * inv, 0.0f), 1.0f);
    float* cw = out + 4 * (size_t)n;
    cw[3 * i + 0] = cx;
    cw[3 * i + 1] = cy;
    cw[3 * i + 2] = cz;
}

// Fast path: stroke params from global via uniform (scalar) loads.
__global__ __launch_bounds__(256) void stroke_kernel(
    const float* __restrict__ coords,
    const float4* __restrict__ A, const float4* __restrict__ B,
    const float* __restrict__ C,
    float* __restrict__ out, int n, int ns)
{
    int i = blockIdx.x * blockDim.x + threadIdx.x;
    if (i >= n) return;

    float cx, cy, cz;
    contract_point(coords, i, cx, cy, cz);
    float m2x = -2.0f * cx, m2y = -2.0f * cy, m2z = -2.0f * cz;
    float c2 = fmaf(cx, cx, fmaf(cy, cy, cz * cz));

    float T = 1.0f, Ad = 0.0f, Ar = 0.0f, Ag = 0.0f, Ab = 0.0f;
#pragma unroll 4
    for (int s = ns - 1; s >= 0; --s) {
        float4 a = A[s];
        float4 b = B[s];
        float cb = C[s];
        float d2 = fmaf(m2x, a.x, fmaf(m2y, a.y, fmaf(m2z, a.z, c2 + a.w)));
        d2 = fmaxf(d2, 0.0f);                       // guard cancellation -> sqrt(neg)
        float dist = __builtin_amdgcn_sqrtf(d2);
        float omt = fminf(fmaxf(fmaf(5.0f, dist, b.x), 0.0f), 1.0f);  // v_med3
        float Tn = omt * T;
        float tT = T - Tn;                           // t * T
        Ad = fmaf(tT, b.y, Ad);
        Ar = fmaf(tT, b.z, Ar);
        Ag = fmaf(tT, b.w, Ag);
        Ab = fmaf(tT, cb, Ab);
        T = Tn;
    }
    write_out(out, i, n, Ad, Ar, Ag, Ab, T, cx, cy, cz);
}

// Fallback (ws too small): same math, stroke params staged+precomputed in LDS.
#define NSTR_MAX 512
__global__ __launch_bounds__(256) void stroke_kernel_lds(
    const float* __restrict__ coords,
    const float* __restrict__ shape, const float* __restrict__ color,
    const float* __restrict__ alpha,
    float* __restrict__ out, int n, int ns)
{
    __shared__ float4 sA[NSTR_MAX];
    __shared__ float4 sB[NSTR_MAX];
    __shared__ float  sC[NSTR_MAX];
    for (int s = threadIdx.x; s < ns; s += blockDim.x) {
        float4 sp = ((const float4*)shape)[s];
        float a2 = fmaf(sp.x, sp.x, fmaf(sp.y, sp.y, sp.z * sp.z));
        sA[s] = make_float4(sp.x, sp.y, sp.z, a2);
        sB[s] = make_float4(fmaf(-5.0f, sp.w, 0.5f),
                            fmaxf(alpha[s], 0.0f) * 50.0f,
                            color[3 * s], color[3 * s + 1]);
        sC[s] = color[3 * s + 2];
    }
    __syncthreads();

    int i = blockIdx.x * blockDim.x + threadIdx.x;
    if (i >= n) return;

    float cx, cy, cz;
    contract_point(coords, i, cx, cy, cz);
    float m2x = -2.0f * cx, m2y = -2.0f * cy, m2z = -2.0f * cz;
    float c2 = fmaf(cx, cx, fmaf(cy, cy, cz * cz));

    float T = 1.0f, Ad = 0.0f, Ar = 0.0f, Ag = 0.0f, Ab = 0.0f;
#pragma unroll 4
    for (int s = ns - 1; s >= 0; --s) {
        float4 a = sA[s];
        float4 b = sB[s];
        float cb = sC[s];
        float d2 = fmaf(m2x, a.x, fmaf(m2y, a.y, fmaf(m2z, a.z, c2 + a.w)));
        d2 = fmaxf(d2, 0.0f);
        float dist = __builtin_amdgcn_sqrtf(d2);
        float omt = fminf(fmaxf(fmaf(5.0f, dist, b.x), 0.0f), 1.0f);
        float Tn = omt * T;
        float tT = T - Tn;
        Ad = fmaf(tT, b.y, Ad);
        Ar = fmaf(tT, b.z, Ar);
        Ag = fmaf(tT, b.w, Ag);
        Ab = fmaf(tT, cb, Ab);
        T = Tn;
    }
    write_out(out, i, n, Ad, Ar, Ag, Ab, T, cx, cy, cz);
}

extern "C" void kernel_launch(void* const* d_in, const int* in_sizes, int n_in,
                              void* d_out, int out_size, void* d_ws, size_t ws_size,
                              hipStream_t stream) {
    const float* coords = (const float*)d_in[0];
    const float* shape  = (const float*)d_in[1];
    const float* color  = (const float*)d_in[2];
    const float* alpha  = (const float*)d_in[3];
    float* out = (float*)d_out;

    int n  = in_sizes[0] / 3;
    int ns = in_sizes[1] / 4;

    const int block = 256;
    int grid = (n + block - 1) / block;

    // ws layout: A float4[ns] @0, B float4[ns] @8192, C float[ns] @16384
    size_t need = 16384 + (size_t)ns * sizeof(float);
    if (ws_size >= need && ns <= 512) {
        float4* A = (float4*)((char*)d_ws + 0);
        float4* B = (float4*)((char*)d_ws + 8192);
        float*  C = (float*)((char*)d_ws + 16384);
        prep_kernel<<<(ns + block - 1) / block, block, 0, stream>>>(
            shape, color, alpha, A, B, C, ns);
        stroke_kernel<<<grid, block, 0, stream>>>(coords, A, B, C, out, n, ns);
    } else {
        stroke_kernel_lds<<<grid, block, 0, stream>>>(
            coords, shape, color, alpha, out, n, ns);
    }
}

// Round 3
// 427.592 us; speedup vs baseline: 1.1863x; 1.1863x over previous
//
#include <hip/hip_runtime.h>

// StrokeField: mip-NeRF-360 contract + 500-sphere sequential alpha blend.
// R1/R2 lesson: limiter is param-fetch LATENCY exposure, not VALU issue.
//  - R2 (s_load/SMEM): SMEM returns out-of-order -> lgkmcnt(0) drain per
//    unroll group -> ~40 cyc/iter exposed. VALUBusy(derived) 78%, 72 cyc/iter.
//  - Fix: LDS staging (ds_read returns IN-ORDER -> fine-grained lgkmcnt) plus
//    source-level prefetch one iteration ahead so unroll groups pipeline.
// Inner loop (back-to-front transmittance, 13 VALU + 1 sqrt):
//   d2  = c2 + a2 - 2 c.a  (3 fma + add + max)
//   omt = clamp(5*dist + (0.5-5r), 0, 1)       (fma + med3)
//   Tn = omt*T; tT = T-Tn; A += tT*{dp,r,g,b}  (mul + sub + 4 fma)

#define NSTR_MAX 512

__global__ __launch_bounds__(256) void stroke_kernel(
    const float* __restrict__ coords,
    const float* __restrict__ shape,
    const float* __restrict__ color,
    const float* __restrict__ alpha,
    float* __restrict__ out, int n, int ns)
{
    // Slot s+1 holds stroke s; slot 0 is a dummy so the prefetch index never
    // underflows (its value is loaded but never used in math).
    __shared__ float4 sA[NSTR_MAX + 1];   // (ax, ay, az, a2)
    __shared__ float4 sB[NSTR_MAX + 1];   // (K = 0.5-5r, dp, ...) see below
    // sB layout: (K, dp, cr, cg); sC holds cb
    __shared__ float  sC[NSTR_MAX + 1];

    for (int s = threadIdx.x; s < ns; s += blockDim.x) {
        float4 sp = ((const float4*)shape)[s];
        float a2 = fmaf(sp.x, sp.x, fmaf(sp.y, sp.y, sp.z * sp.z));
        sA[s + 1] = make_float4(sp.x, sp.y, sp.z, a2);
        sB[s + 1] = make_float4(fmaf(-5.0f, sp.w, 0.5f),
                                fmaxf(alpha[s], 0.0f) * 50.0f,
                                color[3 * s], color[3 * s + 1]);
        sC[s + 1] = color[3 * s + 2];
    }
    __syncthreads();

    int i = blockIdx.x * blockDim.x + threadIdx.x;
    if (i >= n) return;

    float x = coords[3 * i + 0];
    float y = coords[3 * i + 1];
    float z = coords[3 * i + 2];
    float n2 = fmaf(x, x, fmaf(y, y, z * z));
    float nn = fmaxf(__builtin_amdgcn_sqrtf(n2), 1e-9f);
    float invn = 1.0f / nn;
    float sc = (nn <= 1.0f) ? 0.5f : (2.0f - invn) * (0.5f * invn);
    float cx = x * sc, cy = y * sc, cz = z * sc;

    float m2x = -2.0f * cx, m2y = -2.0f * cy, m2z = -2.0f * cz;
    float c2 = fmaf(cx, cx, fmaf(cy, cy, cz * cz));

    float T = 1.0f, Ad = 0.0f, Ar = 0.0f, Ag = 0.0f, Ab = 0.0f;

    // Prefetch stroke ns-1 (slot ns).
    float4 a = sA[ns];
    float4 b = sB[ns];
    float  cB = sC[ns];

#pragma unroll 4
    for (int s = ns - 1; s >= 0; --s) {
        // Prefetch next stroke (s-1, slot s) while computing current one.
        float4 an = sA[s];
        float4 bn = sB[s];
        float  cn = sC[s];

        float d2 = fmaf(m2x, a.x, fmaf(m2y, a.y, fmaf(m2z, a.z, c2 + a.w)));
        d2 = fmaxf(d2, 0.0f);                       // guard fp cancellation
        float dist = __builtin_amdgcn_sqrtf(d2);
        float omt = fminf(fmaxf(fmaf(5.0f, dist, b.x), 0.0f), 1.0f); // v_med3
        float Tn = omt * T;
        float tT = T - Tn;                          // t * T
        Ad = fmaf(tT, b.y, Ad);
        Ar = fmaf(tT, b.z, Ar);
        Ag = fmaf(tT, b.w, Ag);
        Ab = fmaf(tT, cB, Ab);
        T = Tn;

        a = an; b = bn; cB = cn;
    }

    float inv = 1.0f / (1.0f + 1e-6f - T);
    out[i] = Ad;
    float* rgb = out + n;
    rgb[3 * i + 0] = fminf(fmaxf(Ar * inv, 0.0f), 1.0f);
    rgb[3 * i + 1] = fminf(fmaxf(Ag * inv, 0.0f), 1.0f);
    rgb[3 * i + 2] = fminf(fmaxf(Ab * inv, 0.0f), 1.0f);
    float* cw = out + 4 * (size_t)n;
    cw[3 * i + 0] = cx;
    cw[3 * i + 1] = cy;
    cw[3 * i + 2] = cz;
}

extern "C" void kernel_launch(void* const* d_in, const int* in_sizes, int n_in,
                              void* d_out, int out_size, void* d_ws, size_t ws_size,
                              hipStream_t stream) {
    const float* coords = (const float*)d_in[0];
    const float* shape  = (const float*)d_in[1];
    const float* color  = (const float*)d_in[2];
    const float* alpha  = (const float*)d_in[3];
    float* out = (float*)d_out;

    int n  = in_sizes[0] / 3;
    int ns = in_sizes[1] / 4;

    const int block = 256;
    int grid = (n + block - 1) / block;
    stroke_kernel<<<grid, block, 0, stream>>>(coords, shape, color, alpha, out, n, ns);
}

// Round 4
// 405.598 us; speedup vs baseline: 1.2506x; 1.0542x over previous
//
#include <hip/hip_runtime.h>

// StrokeField: mip-NeRF-360 contract + 500-sphere sequential alpha blend.
// R3 post-mortem: 61.6 cyc/wave-iter vs 36-cyc VALU floor -> ~26 cyc/iter of
// per-stroke overhead (3 LDS issues + bookkeeping + residual latency).
// R4: 4 points/thread so each stroke's param fetch (now 2x ds_read_b128,
// diff-form distance, 8 floats/stroke) amortizes over 4 point-blends; 4x ILP
// hides sqrt + LDS latency. Per point-iter: 14 VALU + 1 sqrt, ~0.5 LDS.
//
// Math per (point, stroke), back-to-front transmittance (identical to scan):
//   dx,dy,dz = c - a                      (3 sub)
//   d2 = dx^2+dy^2+dz^2                   (3 fma, >= 0 by construction)
//   dist = sqrt(d2)                       (v_sqrt_f32)
//   omt = clamp(5*dist + (0.5-5r), 0, 1)  (fma + med3)  == 1 - t
//   Tn = omt*T; tT = T - Tn               (mul + sub)
//   {Ad,Ar,Ag,Ab} += tT * {dp,cr,cg,cb}   (4 fma)
//   T = Tn

#define NSTR_MAX 512
#define PTS 4

__global__ __launch_bounds__(256) void stroke_kernel(
    const float* __restrict__ coords,
    const float* __restrict__ shape,
    const float* __restrict__ color,
    const float* __restrict__ alpha,
    float* __restrict__ out, int n, int ns)
{
    // Slot s+1 holds stroke s; slot 0 is a dummy so the last prefetch never
    // underflows (loaded but never used in math).
    __shared__ float4 sA[NSTR_MAX + 1];   // (ax, ay, az, K = 0.5 - 5r)
    __shared__ float4 sB[NSTR_MAX + 1];   // (dp, cr, cg, cb)

    for (int s = threadIdx.x; s < ns; s += blockDim.x) {
        float4 sp = ((const float4*)shape)[s];
        sA[s + 1] = make_float4(sp.x, sp.y, sp.z, fmaf(-5.0f, sp.w, 0.5f));
        sB[s + 1] = make_float4(fmaxf(alpha[s], 0.0f) * 50.0f,
                                color[3 * s], color[3 * s + 1], color[3 * s + 2]);
    }
    __syncthreads();

    const int base = blockIdx.x * (blockDim.x * PTS) + threadIdx.x;

    float cx[PTS], cy[PTS], cz[PTS];
    float T[PTS], Ad[PTS], Ar[PTS], Ag[PTS], Ab[PTS];

#pragma unroll
    for (int k = 0; k < PTS; ++k) {
        int i = base + k * 256;
        i = (i < n) ? i : (n - 1);             // clamp; store is guarded below
        float x = coords[3 * i + 0];
        float y = coords[3 * i + 1];
        float z = coords[3 * i + 2];
        float n2 = fmaf(x, x, fmaf(y, y, z * z));
        float nn = fmaxf(__builtin_amdgcn_sqrtf(n2), 1e-9f);
        float invn = 1.0f / nn;
        float scl = (nn <= 1.0f) ? 0.5f : (2.0f - invn) * (0.5f * invn);
        cx[k] = x * scl; cy[k] = y * scl; cz[k] = z * scl;
        T[k] = 1.0f; Ad[k] = 0.0f; Ar[k] = 0.0f; Ag[k] = 0.0f; Ab[k] = 0.0f;
    }

    // Prefetch stroke ns-1 (slot ns).
    float4 a = sA[ns];
    float4 b = sB[ns];

#pragma unroll 2
    for (int s = ns - 1; s >= 0; --s) {
        // Prefetch next stroke (slot s) while blending the current one.
        float4 an = sA[s];
        float4 bn = sB[s];

#pragma unroll
        for (int k = 0; k < PTS; ++k) {
            float dx = cx[k] - a.x;
            float dy = cy[k] - a.y;
            float dz = cz[k] - a.z;
            float d2 = fmaf(dx, dx, fmaf(dy, dy, dz * dz));
            float dist = __builtin_amdgcn_sqrtf(d2);
            float omt = fminf(fmaxf(fmaf(5.0f, dist, a.w), 0.0f), 1.0f); // med3
            float Tn = omt * T[k];
            float tT = T[k] - Tn;                  // t * T
            Ad[k] = fmaf(tT, b.x, Ad[k]);
            Ar[k] = fmaf(tT, b.y, Ar[k]);
            Ag[k] = fmaf(tT, b.z, Ag[k]);
            Ab[k] = fmaf(tT, b.w, Ab[k]);
            T[k] = Tn;
        }
        a = an; b = bn;
    }

    float* rgb = out + n;
    float* cw  = out + 4 * (size_t)n;
#pragma unroll
    for (int k = 0; k < PTS; ++k) {
        int i = base + k * 256;
        if (i >= n) break;
        float inv = 1.0f / (1.0f + 1e-6f - T[k]);
        out[i] = Ad[k];
        rgb[3 * i + 0] = fminf(fmaxf(Ar[k] * inv, 0.0f), 1.0f);
        rgb[3 * i + 1] = fminf(fmaxf(Ag[k] * inv, 0.0f), 1.0f);
        rgb[3 * i + 2] = fminf(fmaxf(Ab[k] * inv, 0.0f), 1.0f);
        cw[3 * i + 0] = cx[k];
        cw[3 * i + 1] = cy[k];
        cw[3 * i + 2] = cz[k];
    }
}

extern "C" void kernel_launch(void* const* d_in, const int* in_sizes, int n_in,
                              void* d_out, int out_size, void* d_ws, size_t ws_size,
                              hipStream_t stream) {
    const float* coords = (const float*)d_in[0];
    const float* shape  = (const float*)d_in[1];
    const float* color  = (const float*)d_in[2];
    const float* alpha  = (const float*)d_in[3];
    float* out = (float*)d_out;

    int n  = in_sizes[0] / 3;
    int ns = in_sizes[1] / 4;

    const int block = 256;
    int per_block = block * PTS;
    int grid = (n + per_block - 1) / per_block;
    stroke_kernel<<<grid, block, 0, stream>>>(coords, shape, color, alpha, out, n, ns);
}